// Round 2
// baseline (32239.941 us; speedup 1.0000x reference)
//
#include <hip/hip_runtime.h>
#include <stdint.h>

// Problem constants
#define BN 4096
#define TT 20
#define HH 256
#define EE 128
#define KK 5
#define NCOND 5

// ws layout (float/u32 indices)
#define WS_KEYS 0                       // 20*16 u32 (per step: 4 heads x (k1.x,k1.y,k2.x,k2.y))
#define WS_TSC  512                     // 20*1024 cumulative ts@Wk[384:404]
#define WS_WT   20992                   // 75*256 transposed head weights [o][q]
#define WS_BIAS 40192                   // 75 concat biases (pad to 256)
#define WS_G    40448                   // gumbel: [head][t][b][k] 4*20*4096*5
#define WS_ZM   (WS_G + 4*TT*BN*KK)     // normal (B,2) per t: 20*4096*2
#define WS_ZO   (WS_ZM + TT*BN*2)       // normal (B,1) per t per head(y,f,fa): 3*20*4096
#define WS_END  (WS_ZO + 3*TT*BN)       // 2,088,448 floats = 8.35 MB

#define TINYF 1.17549435e-38f
#define LO_N  0.99999994f               // -nextafter(-1,0)

// ---------------- Threefry-2x32 (JAX-exact) ----------------
__device__ __forceinline__ void tf2(uint32_t k0, uint32_t k1, uint32_t x0, uint32_t x1,
                                    uint32_t& o0, uint32_t& o1) {
  const uint32_t ks2 = k0 ^ k1 ^ 0x1BD11BDAu;
  x0 += k0; x1 += k1;
#define RND(r) { x0 += x1; x1 = (x1 << (r)) | (x1 >> (32 - (r))); x1 ^= x0; }
  RND(13) RND(15) RND(26) RND(6)   x0 += k1;  x1 += ks2 + 1u;
  RND(17) RND(29) RND(16) RND(24)  x0 += ks2; x1 += k0 + 2u;
  RND(13) RND(15) RND(26) RND(6)   x0 += k0;  x1 += k1 + 3u;
  RND(17) RND(29) RND(16) RND(24)  x0 += k1;  x1 += ks2 + 4u;
  RND(13) RND(15) RND(26) RND(6)   x0 += ks2; x1 += k0 + 5u;
#undef RND
  o0 = x0; o1 = x1;
}

// jax_threefry_partitionable=True (default since jax 0.4.36):
// random_bits(key,32,shape)[n] = b1 ^ b2 where (b1,b2) = threefry2x32(key, (0, n))
__device__ __forceinline__ uint32_t pbits(uint32_t k0, uint32_t k1, uint32_t n) {
  uint32_t a, b;
  tf2(k0, k1, 0u, n, a, b);
  return a ^ b;
}

__device__ __forceinline__ float u01f(uint32_t bits) {
  return __uint_as_float((bits >> 9) | 0x3f800000u) - 1.0f;
}

// XLA ErfInv32 (math.cc): w = -log1p(-x*x); Giles polynomial
__device__ __forceinline__ float erfinv_f(float x) {
  float w = -log1pf(-x * x);
  float p;
  if (w < 5.0f) {
    w = w - 2.5f;
    p = 2.81022636e-08f;
    p = 3.43273939e-07f + p * w;
    p = -3.5233877e-06f + p * w;
    p = -4.39150654e-06f + p * w;
    p = 0.00021858087f  + p * w;
    p = -0.00125372503f + p * w;
    p = -0.00417768164f + p * w;
    p = 0.246640727f    + p * w;
    p = 1.50140941f     + p * w;
  } else {
    w = sqrtf(w) - 3.0f;
    p = -0.000200214257f;
    p = 0.000100950558f + p * w;
    p = 0.00134934322f  + p * w;
    p = -0.00367342844f + p * w;
    p = 0.00573950773f  + p * w;
    p = -0.0076224613f  + p * w;
    p = 0.00943887047f  + p * w;
    p = 1.00167406f     + p * w;
    p = 2.83297682f     + p * w;
  }
  return p * x;
}

// XLA lowers logistic as 0.5 + 0.5*tanh(0.5x)
__device__ __forceinline__ float sigf(float x) { return 0.5f + 0.5f * tanhf(0.5f * x); }

__device__ __forceinline__ float pick5a(const float* a, int idx) {
  float v = a[0];
#pragma unroll
  for (int k = 1; k < 5; ++k) v = (idx == k) ? a[k] : v;
  return v;
}

// ---------------- prep1: key chain, ts-cumsum, head-weight transpose ----------------
__global__ __launch_bounds__(256) void prep1(
    const float* __restrict__ Wk,
    const float* __restrict__ Wm, const float* __restrict__ bm,
    const float* __restrict__ Wy, const float* __restrict__ by,
    const float* __restrict__ Wf, const float* __restrict__ bf,
    const float* __restrict__ Wfa, const float* __restrict__ bfa,
    float* __restrict__ ws) {
  const int bid = blockIdx.x, tid = threadIdx.x;
  if (bid == 0) {
    // Partitionable (foldlike) split: split(key,n)[i] = threefry2x32(key,(0,i)),
    // full output pair. Chain: key_{t+1} = split_t[0]; km,ky,kf,kfa = split_t[1..4];
    // per head: k1 = split(kh,2)[0] = tf(kh,(0,0)); k2 = split(kh,2)[1] = tf(kh,(0,1)).
    if (tid < 4) {
      uint32_t* keys = (uint32_t*)ws;
      const int l = tid;                 // head: 0=km 1=ky 2=kf 3=kfa
      uint32_t kx = 0u, ky = 42u;        // jax.random.key(42) -> [0, 42]
      for (int t = 0; t < TT; ++t) {
        uint32_t hx, hy;
        tf2(kx, ky, 0u, (uint32_t)(l + 1), hx, hy);
        uint32_t k1x, k1y, k2x, k2y;
        tf2(hx, hy, 0u, 0u, k1x, k1y);
        tf2(hx, hy, 0u, 1u, k2x, k2y);
        keys[t * 16 + l * 4 + 0] = k1x;
        keys[t * 16 + l * 4 + 1] = k1y;
        keys[t * 16 + l * 4 + 2] = k2x;
        keys[t * 16 + l * 4 + 3] = k2y;
        uint32_t nx, ny;
        tf2(kx, ky, 0u, 0u, nx, ny);     // next carry key
        kx = nx; ky = ny;
      }
    }
  } else if (bid <= 4) {
    const int col = (bid - 1) * 256 + tid;
    float s = 0.0f;
    for (int p = 0; p < TT; ++p) {
      s += Wk[(size_t)(EE + HH + p) * 1024 + col];
      ws[WS_TSC + p * 1024 + col] = s;
    }
  } else {
    const int idx = (bid - 5) * 256 + tid;
    if (idx < 75 * 256) {
      const int o = idx >> 8, q = idx & 255;
      float v;
      if (o < 30)      v = Wm[q * 30 + o];
      else if (o < 45) v = Wy[q * 15 + (o - 30)];
      else if (o < 60) v = Wf[q * 15 + (o - 45)];
      else             v = Wfa[q * 15 + (o - 60)];
      ws[WS_WT + idx] = v;
    } else if (idx < 75 * 256 + 75) {
      const int o = idx - 75 * 256;
      float v = (o < 30) ? bm[o] : (o < 45) ? by[o - 30] : (o < 60) ? bf[o - 45] : bfa[o - 60];
      ws[WS_BIAS + o] = v;
    }
  }
}

// ---------------- prep2: all gumbel/normal draws (data-independent) ----------------
__global__ __launch_bounds__(256) void prep2(float* __restrict__ ws) {
  const uint32_t* keys = (const uint32_t*)ws;
  const int id = blockIdx.x * 256 + threadIdx.x;
  const int NGg = 4 * TT * BN * KK;
  if (id < NGg) {
    const int head = id / (TT * BN * KK);
    const int r1 = id % (TT * BN * KK);
    const int t = r1 / (BN * KK);
    const uint32_t n = (uint32_t)(r1 % (BN * KK));
    const uint32_t k0 = keys[t * 16 + head * 4 + 0], k1 = keys[t * 16 + head * 4 + 1];
    const uint32_t bits = pbits(k0, k1, n);
    float u = fmaxf(TINYF, u01f(bits) * (1.0f - TINYF) + TINYF);
    ws[WS_G + id] = -logf(-logf(u));
  } else if (id < NGg + TT * BN * 2) {
    const int jj = id - NGg;
    const int t = jj / (BN * 2);
    const uint32_t n = (uint32_t)(jj % (BN * 2));
    const uint32_t k0 = keys[t * 16 + 2], k1 = keys[t * 16 + 3];
    const uint32_t bits = pbits(k0, k1, n);
    float u = u01f(bits) * 2.0f - LO_N;   // (hi-lo) rounds to 2.0f exactly
    u = fmaxf(-LO_N, u);
    ws[WS_ZM + jj] = 1.41421356f * erfinv_f(u);
  } else if (id < NGg + TT * BN * 2 + 3 * TT * BN) {
    const int jj = id - NGg - TT * BN * 2;
    const int head = jj / (TT * BN);
    const int r2 = jj % (TT * BN);
    const int t = r2 / BN;
    const uint32_t n = (uint32_t)(r2 % BN);
    const uint32_t k0 = keys[t * 16 + (head + 1) * 4 + 2], k1 = keys[t * 16 + (head + 1) * 4 + 3];
    const uint32_t bits = pbits(k0, k1, n);
    float u = u01f(bits) * 2.0f - LO_N;
    u = fmaxf(-LO_N, u);
    ws[WS_ZO + jj] = 1.41421356f * erfinv_f(u);
  }
}

// ---------------- main: 20 fused decode steps, 16 rows/block ----------------
__global__ __launch_bounds__(512, 2) void decode_main(
    const float* __restrict__ conditions, const float* __restrict__ state_h,
    const float* __restrict__ state_c, const float* __restrict__ We1,
    const float* __restrict__ be1, const float* __restrict__ We2,
    const float* __restrict__ be2, const float* __restrict__ Wk,
    const float* __restrict__ Wr, const float* __restrict__ bl,
    const float* __restrict__ ws, float* __restrict__ out) {
  __shared__ float We2s[EE * EE];     // 64 KB
  __shared__ float e2s[16 * EE];      // 8 KB
  __shared__ float Ubuf[16 * HH];     // 16 KB: state_h staging -> e1 -> h (disjoint lifetimes)
  __shared__ float ps[16 * 80];       // 5 KB head outputs
  __shared__ float conds[16 * 8];     // carry

  const int tid = threadIdx.x;
  const int row0 = blockIdx.x * 16;
  const int u = tid & 255;            // hidden unit / z column base
  const int rh = tid >> 8;            // row half: rows rh*8 .. rh*8+7

  for (int i = tid; i < EE * EE; i += 512) We2s[i] = We2[i];
  for (int i = tid; i < 16 * NCOND; i += 512) {
    int r = i / NCOND, c = i % NCOND;
    conds[r * 8 + c] = conditions[(size_t)(row0 + r) * (TT * NCOND) + c];  // [:,0,:]
  }
  for (int i = tid; i < 16 * HH; i += 512) Ubuf[i] = state_h[(size_t)row0 * HH + i];
  float sc[8];
#pragma unroll
  for (int rr = 0; rr < 8; ++rr) sc[rr] = state_c[(size_t)(row0 + rh * 8 + rr) * HH + u];
  __syncthreads();

  // step-invariant: cz = bl + state_h @ (Wk[128:384] + Wr), kept in registers
  float cz0[8], cz1[8], cz2[8], cz3[8];
  {
    const float bl0 = bl[u], bl1 = bl[256 + u], bl2 = bl[512 + u], bl3 = bl[768 + u];
#pragma unroll
    for (int rr = 0; rr < 8; ++rr) { cz0[rr] = bl0; cz1[rr] = bl1; cz2[rr] = bl2; cz3[rr] = bl3; }
    for (int q = 0; q < HH; q += 4) {
      float4 ev[8];
#pragma unroll
      for (int rr = 0; rr < 8; ++rr) ev[rr] = *(const float4*)&Ubuf[(rh * 8 + rr) * HH + q];
#pragma unroll
      for (int qq = 0; qq < 4; ++qq) {
        const size_t rk = (size_t)(EE + q + qq) * 1024;
        const size_t rw = (size_t)(q + qq) * 1024;
        const float w0 = Wk[rk + u]       + Wr[rw + u];
        const float w1 = Wk[rk + 256 + u] + Wr[rw + 256 + u];
        const float w2 = Wk[rk + 512 + u] + Wr[rw + 512 + u];
        const float w3 = Wk[rk + 768 + u] + Wr[rw + 768 + u];
#pragma unroll
        for (int rr = 0; rr < 8; ++rr) {
          const float e = (qq == 0) ? ev[rr].x : (qq == 1) ? ev[rr].y : (qq == 2) ? ev[rr].z : ev[rr].w;
          cz0[rr] = fmaf(e, w0, cz0[rr]);
          cz1[rr] = fmaf(e, w1, cz1[rr]);
          cz2[rr] = fmaf(e, w2, cz2[rr]);
          cz3[rr] = fmaf(e, w3, cz3[rr]);
        }
      }
    }
  }
  __syncthreads();   // Ubuf(state_h) dead; becomes e1/h scratch

  for (int t = 0; t < TT; ++t) {
    // ---- E1: e1 = cond @ We1 + be1 -> Ubuf[0..2048)
    {
      const int r = tid >> 5, j0 = (tid & 31) * 4;
      const float c0 = conds[r * 8 + 0], c1 = conds[r * 8 + 1], c2 = conds[r * 8 + 2],
                  c3 = conds[r * 8 + 3], c4 = conds[r * 8 + 4];
#pragma unroll
      for (int jj = 0; jj < 4; ++jj) {
        const int j = j0 + jj;
        float a = be1[j];
        a = fmaf(c0, We1[0 * EE + j], a);
        a = fmaf(c1, We1[1 * EE + j], a);
        a = fmaf(c2, We1[2 * EE + j], a);
        a = fmaf(c3, We1[3 * EE + j], a);
        a = fmaf(c4, We1[4 * EE + j], a);
        Ubuf[r * EE + j] = a;
      }
    }
    __syncthreads();
    // ---- E2: e2 = e1 @ We2 + be2
    {
      const int r = tid >> 5, j0 = (tid & 31) * 4;
      float a0 = be2[j0], a1 = be2[j0 + 1], a2 = be2[j0 + 2], a3 = be2[j0 + 3];
      for (int q = 0; q < EE; ++q) {
        const float e = Ubuf[r * EE + q];
        const float4 w = *(const float4*)&We2s[q * EE + j0];
        a0 = fmaf(e, w.x, a0); a1 = fmaf(e, w.y, a1);
        a2 = fmaf(e, w.z, a2); a3 = fmaf(e, w.w, a3);
      }
      *(float4*)&e2s[r * EE + j0] = make_float4(a0, a1, a2, a3);
    }
    __syncthreads();
    // ---- Z: z = e2 @ Wk[0:128] + cz + tscum[t]; gates -> h -> Ubuf
    {
      float ai[8], af[8], ag[8], ao[8];
      const float ti = ws[WS_TSC + t * 1024 + u];
      const float tf_ = ws[WS_TSC + t * 1024 + 256 + u];
      const float tg = ws[WS_TSC + t * 1024 + 512 + u];
      const float to = ws[WS_TSC + t * 1024 + 768 + u];
#pragma unroll
      for (int rr = 0; rr < 8; ++rr) {
        ai[rr] = cz0[rr] + ti; af[rr] = cz1[rr] + tf_;
        ag[rr] = cz2[rr] + tg; ao[rr] = cz3[rr] + to;
      }
      for (int q = 0; q < EE; q += 4) {
        float4 ev[8];
#pragma unroll
        for (int rr = 0; rr < 8; ++rr) ev[rr] = *(const float4*)&e2s[(rh * 8 + rr) * EE + q];
#pragma unroll
        for (int qq = 0; qq < 4; ++qq) {
          const size_t rw = (size_t)(q + qq) * 1024;
          const float wi = Wk[rw + u];
          const float wf = Wk[rw + 256 + u];
          const float wg = Wk[rw + 512 + u];
          const float wo = Wk[rw + 768 + u];
#pragma unroll
          for (int rr = 0; rr < 8; ++rr) {
            const float e = (qq == 0) ? ev[rr].x : (qq == 1) ? ev[rr].y : (qq == 2) ? ev[rr].z : ev[rr].w;
            ai[rr] = fmaf(e, wi, ai[rr]);
            af[rr] = fmaf(e, wf, af[rr]);
            ag[rr] = fmaf(e, wg, ag[rr]);
            ao[rr] = fmaf(e, wo, ao[rr]);
          }
        }
      }
#pragma unroll
      for (int rr = 0; rr < 8; ++rr) {
        const float cv = sigf(af[rr]) * sc[rr] + sigf(ai[rr]) * tanhf(ag[rr]);
        const float hv = sigf(ao[rr]) * tanhf(cv);
        Ubuf[(rh * 8 + rr) * HH + u] = hv;
      }
    }
    __syncthreads();
    // ---- Heads: p[o] = h @ WT[o] + bias[o], o in [0,75)
    {
      const int r = tid >> 5, jg = tid & 31;
#pragma unroll
      for (int s = 0; s < 3; ++s) {
        const int o = jg + 32 * s;
        if (o < 75) {
          float acc = ws[WS_BIAS + o];
          const float* wt = &ws[WS_WT + o * 256];
          for (int q = 0; q < HH; q += 4) {
            const float4 w = *(const float4*)&wt[q];
            const float4 hv = *(const float4*)&Ubuf[r * HH + q];
            acc = fmaf(hv.x, w.x, acc); acc = fmaf(hv.y, w.y, acc);
            acc = fmaf(hv.z, w.z, acc); acc = fmaf(hv.w, w.w, acc);
          }
          ps[r * 80 + o] = acc;
        }
      }
    }
    __syncthreads();
    // ---- Sampling + vec outputs: lane per (row, head)
    {
      const int r = tid >> 5, sub = tid & 31;
      if (sub < 4) {
        const int head = sub;
        const int row = row0 + r;
        const int base = (head == 0) ? 0 : (30 + 15 * (head - 1));
        float l[5];
#pragma unroll
        for (int k = 0; k < 5; ++k) l[k] = ps[r * 80 + base + k];
        const float mx = fmaxf(fmaxf(fmaxf(l[0], l[1]), fmaxf(l[2], l[3])), l[4]);
        float e[5]; float ssum = 0.0f;
#pragma unroll
        for (int k = 0; k < 5; ++k) { e[k] = expf(l[k] - mx); ssum += e[k]; }
        // categorical = argmax(logits + gumbel), first-max wins
        const float* G = &ws[WS_G + ((size_t)head * TT + t) * (BN * KK) + (size_t)row * KK];
        int idx = 0; float best = l[0] + G[0];
#pragma unroll
        for (int k = 1; k < 5; ++k) { const float v = l[k] + G[k]; if (v > best) { best = v; idx = k; } }
        if (head == 0) {
          const size_t ob = ((size_t)row * TT + t) * 30;
          float mu_lo[5], s_lo[5], mu_la[5], s_la[5], rho[5];
#pragma unroll
          for (int k = 0; k < 5; ++k) {
            mu_lo[k] = ps[r * 80 + 5 + k];
            s_lo[k] = expf(ps[r * 80 + 10 + k]);
            mu_la[k] = ps[r * 80 + 15 + k];
            s_la[k] = expf(ps[r * 80 + 20 + k]);
            rho[k] = tanhf(ps[r * 80 + 25 + k]);
          }
#pragma unroll
          for (int k = 0; k < 5; ++k) {
            out[ob + k] = e[k] / ssum;
            out[ob + 5 + k] = mu_lo[k];
            out[ob + 10 + k] = s_lo[k];
            out[ob + 15 + k] = mu_la[k];
            out[ob + 20 + k] = s_la[k];
            out[ob + 25 + k] = rho[k];
          }
          const float z0 = ws[WS_ZM + t * (BN * 2) + row * 2 + 0];
          const float z1 = ws[WS_ZM + t * (BN * 2) + row * 2 + 1];
          const float xlo = pick5a(mu_lo, idx) + pick5a(s_lo, idx) * z0;
          const float rr_ = pick5a(rho, idx);
          const float xla = pick5a(mu_la, idx) +
                            pick5a(s_la, idx) * (rr_ * z0 + sqrtf(1.0f - rr_ * rr_) * z1);
          conds[r * 8 + 0] = xlo;
          conds[r * 8 + 1] = xla;
        } else {
          const size_t ob = (size_t)BN * TT * 30 + (size_t)(head - 1) * BN * TT * 15 +
                            ((size_t)row * TT + t) * 15;
          float mu[5], sg[5];
#pragma unroll
          for (int k = 0; k < 5; ++k) {
            mu[k] = ps[r * 80 + base + 5 + k];
            sg[k] = expf(ps[r * 80 + base + 10 + k]);
          }
#pragma unroll
          for (int k = 0; k < 5; ++k) {
            out[ob + k] = e[k] / ssum;
            out[ob + 5 + k] = mu[k];
            out[ob + 10 + k] = sg[k];
          }
          const float zz = ws[WS_ZO + ((size_t)(head - 1) * TT + t) * BN + row];
          conds[r * 8 + 1 + head] = pick5a(mu, idx) + pick5a(sg, idx) * zz;
        }
      }
    }
    __syncthreads();
  }
}

extern "C" void kernel_launch(void* const* d_in, const int* in_sizes, int n_in,
                              void* d_out, int out_size, void* d_ws, size_t ws_size,
                              hipStream_t stream) {
  const float* conditions = (const float*)d_in[0];
  const float* state_h = (const float*)d_in[1];
  const float* state_c = (const float*)d_in[2];
  // d_in[3] = steps_n (=20, compile-time TT)
  const float* We1 = (const float*)d_in[4];
  const float* be1 = (const float*)d_in[5];
  const float* We2 = (const float*)d_in[6];
  const float* be2 = (const float*)d_in[7];
  const float* Wk  = (const float*)d_in[8];
  const float* Wr  = (const float*)d_in[9];
  const float* bl  = (const float*)d_in[10];
  const float* Wm  = (const float*)d_in[11];
  const float* bm  = (const float*)d_in[12];
  const float* Wy  = (const float*)d_in[13];
  const float* by  = (const float*)d_in[14];
  const float* Wf  = (const float*)d_in[15];
  const float* bf  = (const float*)d_in[16];
  const float* Wfa = (const float*)d_in[17];
  const float* bfa = (const float*)d_in[18];
  float* ws = (float*)d_ws;   // needs WS_END*4 ≈ 8.4 MB
  float* out = (float*)d_out;

  prep1<<<dim3(81), dim3(256), 0, stream>>>(Wk, Wm, bm, Wy, by, Wf, bf, Wfa, bfa, ws);
  prep2<<<dim3(8000), dim3(256), 0, stream>>>(ws);
  decode_main<<<dim3(BN / 16), dim3(512), 0, stream>>>(
      conditions, state_h, state_c, We1, be1, We2, be2, Wk, Wr, bl, ws, out);
}

// Round 4
// 31032.355 us; speedup vs baseline: 1.0389x; 1.0389x over previous
//
#include <hip/hip_runtime.h>
#include <stdint.h>

// Problem constants
#define BN 4096
#define TT 20
#define HH 256
#define EE 128
#define KK 5
#define NCOND 5

// ws layout (float/u32 indices)
#define WS_KEYS 0                       // 20*16 u32 (per step: 4 heads x (k1.x,k1.y,k2.x,k2.y))
#define WS_TSC  512                     // 20*1024 cumulative ts@Wk[384:404]
#define WS_WT   20992                   // 75*256 transposed head weights [o][q]
#define WS_BIAS 40192                   // 75 concat biases (pad to 256)
#define WS_BAR  40448                   // 32 clusters x 32 u32 barrier counters
#define WS_E2   41472                   // e2 shuttle: 4096*128 f32
#define WS_H    565760                  // h shuttle: 4096*256 f32
#define WS_END  1614336                 // 6.46 MB

#define TINYF 1.17549435e-38f
#define LO_N  0.99999994f               // -nextafter(-1,0)

// ---------------- Threefry-2x32 (JAX-exact) ----------------
__device__ __forceinline__ void tf2(uint32_t k0, uint32_t k1, uint32_t x0, uint32_t x1,
                                    uint32_t& o0, uint32_t& o1) {
  const uint32_t ks2 = k0 ^ k1 ^ 0x1BD11BDAu;
  x0 += k0; x1 += k1;
#define RND(r) { x0 += x1; x1 = (x1 << (r)) | (x1 >> (32 - (r))); x1 ^= x0; }
  RND(13) RND(15) RND(26) RND(6)   x0 += k1;  x1 += ks2 + 1u;
  RND(17) RND(29) RND(16) RND(24)  x0 += ks2; x1 += k0 + 2u;
  RND(13) RND(15) RND(26) RND(6)   x0 += k0;  x1 += k1 + 3u;
  RND(17) RND(29) RND(16) RND(24)  x0 += k1;  x1 += ks2 + 4u;
  RND(13) RND(15) RND(26) RND(6)   x0 += ks2; x1 += k0 + 5u;
#undef RND
  o0 = x0; o1 = x1;
}

// jax_threefry_partitionable: bits[n] = a ^ b, (a,b) = threefry2x32(key, (0, n))
__device__ __forceinline__ uint32_t pbits(uint32_t k0, uint32_t k1, uint32_t n) {
  uint32_t a, b;
  tf2(k0, k1, 0u, n, a, b);
  return a ^ b;
}

__device__ __forceinline__ float u01f(uint32_t bits) {
  return __uint_as_float((bits >> 9) | 0x3f800000u) - 1.0f;
}

// XLA ErfInv32 (Giles polynomial)
__device__ __forceinline__ float erfinv_f(float x) {
  float w = -log1pf(-x * x);
  float p;
  if (w < 5.0f) {
    w = w - 2.5f;
    p = 2.81022636e-08f;
    p = 3.43273939e-07f + p * w;
    p = -3.5233877e-06f + p * w;
    p = -4.39150654e-06f + p * w;
    p = 0.00021858087f  + p * w;
    p = -0.00125372503f + p * w;
    p = -0.00417768164f + p * w;
    p = 0.246640727f    + p * w;
    p = 1.50140941f     + p * w;
  } else {
    w = sqrtf(w) - 3.0f;
    p = -0.000200214257f;
    p = 0.000100950558f + p * w;
    p = 0.00134934322f  + p * w;
    p = -0.00367342844f + p * w;
    p = 0.00573950773f  + p * w;
    p = -0.0076224613f  + p * w;
    p = 0.00943887047f  + p * w;
    p = 1.00167406f     + p * w;
    p = 2.83297682f     + p * w;
  }
  return p * x;
}

// XLA lowers logistic as 0.5 + 0.5*tanh(0.5x)
__device__ __forceinline__ float sigf(float x) { return 0.5f + 0.5f * tanhf(0.5f * x); }

__device__ __forceinline__ float pick5a(const float* a, int idx) {
  float v = a[0];
#pragma unroll
  for (int k = 1; k < 5; ++k) v = (idx == k) ? a[k] : v;
  return v;
}

// ---------------- prep1: key chain, ts-cumsum, head-weight transpose, barrier init ----
__global__ __launch_bounds__(256) void prep1(
    const float* __restrict__ Wk,
    const float* __restrict__ Wm, const float* __restrict__ bm,
    const float* __restrict__ Wy, const float* __restrict__ by,
    const float* __restrict__ Wf, const float* __restrict__ bf,
    const float* __restrict__ Wfa, const float* __restrict__ bfa,
    float* __restrict__ ws) {
  const int bid = blockIdx.x, tid = threadIdx.x;
  if (bid == 0) {
    if (tid < 4) {
      uint32_t* keys = (uint32_t*)ws;
      const int l = tid;                 // head: 0=km 1=ky 2=kf 3=kfa
      uint32_t kx = 0u, ky = 42u;        // jax.random.key(42)
      for (int t = 0; t < TT; ++t) {
        uint32_t hx, hy;
        tf2(kx, ky, 0u, (uint32_t)(l + 1), hx, hy);
        uint32_t k1x, k1y, k2x, k2y;
        tf2(hx, hy, 0u, 0u, k1x, k1y);
        tf2(hx, hy, 0u, 1u, k2x, k2y);
        keys[t * 16 + l * 4 + 0] = k1x;
        keys[t * 16 + l * 4 + 1] = k1y;
        keys[t * 16 + l * 4 + 2] = k2x;
        keys[t * 16 + l * 4 + 3] = k2y;
        uint32_t nx, ny;
        tf2(kx, ky, 0u, 0u, nx, ny);
        kx = nx; ky = ny;
      }
    }
  } else if (bid <= 4) {
    const int col = (bid - 1) * 256 + tid;
    float s = 0.0f;
    for (int p = 0; p < TT; ++p) {
      s += Wk[(size_t)(EE + HH + p) * 1024 + col];
      ws[WS_TSC + p * 1024 + col] = s;
    }
  } else if (bid <= 81) {
    const int idx = (bid - 5) * 256 + tid;
    if (idx < 75 * 256) {
      const int o = idx >> 8, q = idx & 255;
      float v;
      if (o < 30)      v = Wm[q * 30 + o];
      else if (o < 45) v = Wy[q * 15 + (o - 30)];
      else if (o < 60) v = Wf[q * 15 + (o - 45)];
      else             v = Wfa[q * 15 + (o - 60)];
      ws[WS_WT + idx] = v;
    } else if (idx < 75 * 256 + 75) {
      const int o = idx - 75 * 256;
      float v = (o < 30) ? bm[o] : (o < 45) ? by[o - 30] : (o < 60) ? bf[o - 45] : bfa[o - 60];
      ws[WS_BIAS + o] = v;
    }
  } else {
    // zero ALL 1024 cluster-barrier counters every launch (256 threads -> stride)
    for (int i = tid; i < 1024; i += 256) ((uint32_t*)ws)[WS_BAR + i] = 0u;
  }
}

// ---- lightweight intra-cluster (8-block) barrier; monotone counter ----
__device__ __forceinline__ void cbar(uint32_t* bar, int tid, uint32_t target) {
  __syncthreads();   // drains vmcnt(0): all block's global stores complete before release
  if (tid == 0) {
    __threadfence();
    __hip_atomic_fetch_add(bar, 1u, __ATOMIC_RELEASE, __HIP_MEMORY_SCOPE_AGENT);
    while (__hip_atomic_load(bar, __ATOMIC_ACQUIRE, __HIP_MEMORY_SCOPE_AGENT) < target) {
      __builtin_amdgcn_s_sleep(2);
    }
    __threadfence();
  }
  __syncthreads();
}

// ---------------- main: cooperative, cluster-of-8 col/row partitioned ----------------
// cluster cl = b&31 owns rows 128cl..128cl+128 (mates b=cl+32j share b%8 -> same XCD
// under round-robin; correctness does not depend on it, only barrier latency).
// col-role (phase Z): block owns units u0=32j..+32 for the cluster's 128 rows.
// row-role (phases E/heads): block owns rows myrow0=128cl+16j..+16.
__global__ __launch_bounds__(512, 2) void decode_main(
    const float* __restrict__ conditions, const float* __restrict__ state_h,
    const float* __restrict__ state_c, const float* __restrict__ We1,
    const float* __restrict__ be1, const float* __restrict__ We2,
    const float* __restrict__ be2, const float* __restrict__ Wk,
    const float* __restrict__ Wr, const float* __restrict__ bl,
    float* __restrict__ ws, float* __restrict__ out) {
  __shared__ float WkS[128 * 128];    // 64 KB: z-weights slice [q][gate*32+uu], resident
  __shared__ float e2B[128 * 128];    // 64 KB: phase-Z e2 tile / phase-heads h tile / cz h-stage
  __shared__ float e1s[16 * EE];      // 8 KB
  __shared__ float ps[16 * 80];       // 5 KB
  __shared__ float conds[16 * 8];
  __shared__ uint32_t keysL[TT * 16];

  const int tid = threadIdx.x;
  const int b = blockIdx.x;
  const int cl = b & 31;
  const int jslice = b >> 5;
  const int rbase = cl * 128;
  const int u0 = jslice * 32;
  const int myrow0 = rbase + jslice * 16;

  uint32_t* bar = (uint32_t*)ws + WS_BAR + cl * 32;
  uint32_t bcnt = 0;

  // ---- prologue: stage resident data ----
  for (int i = tid; i < 128 * 128; i += 512) {
    const int q = i >> 7, cc = i & 127;
    WkS[i] = Wk[(size_t)q * 1024 + (cc >> 5) * 256 + u0 + (cc & 31)];
  }
  for (int i = tid; i < TT * 16; i += 512) keysL[i] = ((const uint32_t*)ws)[i];
  for (int i = tid; i < 16 * NCOND; i += 512) {
    const int r = i / NCOND, cc = i % NCOND;
    conds[r * 8 + cc] = conditions[(size_t)(myrow0 + r) * (TT * NCOND) + cc];  // [:,0,:]
  }
  const int rt = tid >> 5, uu = tid & 31;
  const int myu = u0 + uu;
  float sc[8];  // state_c is CONSTANT across steps (reference semantics)
#pragma unroll
  for (int rr = 0; rr < 8; ++rr) sc[rr] = state_c[(size_t)(rbase + rt * 8 + rr) * HH + myu];
  __syncthreads();

  // ---- step-invariant cz = bl + state_h @ (Wk[128:384] + Wr), col-role registers ----
  float cz0[8], cz1[8], cz2[8], cz3[8];
  {
    const float bl0 = bl[myu], bl1 = bl[256 + myu], bl2 = bl[512 + myu], bl3 = bl[768 + myu];
#pragma unroll
    for (int rr = 0; rr < 8; ++rr) { cz0[rr] = bl0; cz1[rr] = bl1; cz2[rr] = bl2; cz3[rr] = bl3; }
    for (int ch = 0; ch < 2; ++ch) {
      for (int i = tid; i < 4096; i += 512) {   // stage state_h[:,ch*128..+128] for 128 rows
        const int lr = i >> 5, q4 = (i & 31) << 2;
        *(float4*)&e2B[lr * 128 + q4] =
            *(const float4*)&state_h[(size_t)(rbase + lr) * HH + ch * 128 + q4];
      }
      __syncthreads();
      for (int q = 0; q < 128; q += 4) {
        float4 ev[8];
#pragma unroll
        for (int rr = 0; rr < 8; ++rr) ev[rr] = *(const float4*)&e2B[(rt * 8 + rr) * 128 + q];
#pragma unroll
        for (int qq = 0; qq < 4; ++qq) {
          const int qg = ch * 128 + q + qq;
          const size_t rk = (size_t)(EE + qg) * 1024;
          const size_t rw = (size_t)qg * 1024;
          const float w0 = Wk[rk + myu]       + Wr[rw + myu];
          const float w1 = Wk[rk + 256 + myu] + Wr[rw + 256 + myu];
          const float w2 = Wk[rk + 512 + myu] + Wr[rw + 512 + myu];
          const float w3 = Wk[rk + 768 + myu] + Wr[rw + 768 + myu];
#pragma unroll
          for (int rr = 0; rr < 8; ++rr) {
            const float e = (qq == 0) ? ev[rr].x : (qq == 1) ? ev[rr].y
                          : (qq == 2) ? ev[rr].z : ev[rr].w;
            cz0[rr] = fmaf(e, w0, cz0[rr]);
            cz1[rr] = fmaf(e, w1, cz1[rr]);
            cz2[rr] = fmaf(e, w2, cz2[rr]);
            cz3[rr] = fmaf(e, w3, cz3[rr]);
          }
        }
      }
      __syncthreads();
    }
  }

  for (int t = 0; t < TT; ++t) {
    // ---- Phase 1 (row-role): e1 = cond@We1+be1 ; e2 = e1@We2+be2 -> ws_e2 ----
    {
      const int r = tid >> 5, j0 = (tid & 31) * 4;
      const float c0 = conds[r * 8 + 0], c1 = conds[r * 8 + 1], c2 = conds[r * 8 + 2],
                  c3 = conds[r * 8 + 3], c4 = conds[r * 8 + 4];
#pragma unroll
      for (int jj = 0; jj < 4; ++jj) {
        const int j = j0 + jj;
        float a = be1[j];
        a = fmaf(c0, We1[0 * EE + j], a);
        a = fmaf(c1, We1[1 * EE + j], a);
        a = fmaf(c2, We1[2 * EE + j], a);
        a = fmaf(c3, We1[3 * EE + j], a);
        a = fmaf(c4, We1[4 * EE + j], a);
        e1s[r * EE + j] = a;
      }
    }
    __syncthreads();
    {
      const int r = tid >> 5, j0 = (tid & 31) * 4;
      float a0 = be2[j0], a1 = be2[j0 + 1], a2 = be2[j0 + 2], a3 = be2[j0 + 3];
      for (int q = 0; q < EE; ++q) {
        const float e = e1s[r * EE + q];
        const float4 w = *(const float4*)&We2[q * EE + j0];
        a0 = fmaf(e, w.x, a0); a1 = fmaf(e, w.y, a1);
        a2 = fmaf(e, w.z, a2); a3 = fmaf(e, w.w, a3);
      }
      *(float4*)&ws[WS_E2 + (size_t)(myrow0 + r) * EE + j0] = make_float4(a0, a1, a2, a3);
    }
    cbar(bar, tid, 8u * (++bcnt));

    // ---- Phase 2 (col-role): z = e2@WkS + cz + tsc[t]; gates -> h -> ws_h ----
    {
      for (int i = tid; i < 4096; i += 512) {   // stage cluster e2 tile
        const int lr = i >> 5, q4 = (i & 31) << 2;
        *(float4*)&e2B[lr * 128 + q4] =
            *(const float4*)&ws[WS_E2 + (size_t)(rbase + lr) * EE + q4];
      }
      __syncthreads();
      float ai[8], af[8], ag[8], ao[8];
      const float ti  = ws[WS_TSC + t * 1024 + myu];
      const float tf_ = ws[WS_TSC + t * 1024 + 256 + myu];
      const float tg  = ws[WS_TSC + t * 1024 + 512 + myu];
      const float to  = ws[WS_TSC + t * 1024 + 768 + myu];
#pragma unroll
      for (int rr = 0; rr < 8; ++rr) {
        ai[rr] = cz0[rr] + ti; af[rr] = cz1[rr] + tf_;
        ag[rr] = cz2[rr] + tg; ao[rr] = cz3[rr] + to;
      }
      for (int q = 0; q < EE; q += 4) {
        float4 ev[8];
#pragma unroll
        for (int rr = 0; rr < 8; ++rr) ev[rr] = *(const float4*)&e2B[(rt * 8 + rr) * 128 + q];
#pragma unroll
        for (int qq = 0; qq < 4; ++qq) {
          const float wi = WkS[(q + qq) * 128 + uu];
          const float wf = WkS[(q + qq) * 128 + 32 + uu];
          const float wg = WkS[(q + qq) * 128 + 64 + uu];
          const float wo = WkS[(q + qq) * 128 + 96 + uu];
#pragma unroll
          for (int rr = 0; rr < 8; ++rr) {
            const float e = (qq == 0) ? ev[rr].x : (qq == 1) ? ev[rr].y
                          : (qq == 2) ? ev[rr].z : ev[rr].w;
            ai[rr] = fmaf(e, wi, ai[rr]);
            af[rr] = fmaf(e, wf, af[rr]);
            ag[rr] = fmaf(e, wg, ag[rr]);
            ao[rr] = fmaf(e, wo, ao[rr]);
          }
        }
      }
#pragma unroll
      for (int rr = 0; rr < 8; ++rr) {
        const float cv = sigf(af[rr]) * sc[rr] + sigf(ai[rr]) * tanhf(ag[rr]);
        const float hv = sigf(ao[rr]) * tanhf(cv);
        ws[WS_H + (size_t)(rbase + rt * 8 + rr) * HH + myu] = hv;
      }
    }
    cbar(bar, tid, 8u * (++bcnt));

    // ---- Phase 3 (row-role): heads + sampling + outputs + cond update ----
    {
      for (int i = tid; i < 1024; i += 512) {   // stage h rows into e2B (alias)
        const int r = i >> 6, q4 = (i & 63) << 2;
        *(float4*)&e2B[r * HH + q4] =
            *(const float4*)&ws[WS_H + (size_t)(myrow0 + r) * HH + q4];
      }
      __syncthreads();
      const int r = tid >> 5, jg = tid & 31;
#pragma unroll
      for (int s = 0; s < 3; ++s) {
        const int o = jg + 32 * s;
        if (o < 75) {
          float acc = ws[WS_BIAS + o];
          const float* wt = &ws[WS_WT + o * 256];
          for (int q = 0; q < HH; q += 4) {
            const float4 w = *(const float4*)&wt[q];
            const float4 hv = *(const float4*)&e2B[r * HH + q];
            acc = fmaf(hv.x, w.x, acc); acc = fmaf(hv.y, w.y, acc);
            acc = fmaf(hv.z, w.z, acc); acc = fmaf(hv.w, w.w, acc);
          }
          ps[r * 80 + o] = acc;
        }
      }
      __syncthreads();
      const int sub = tid & 31;
      if (sub < 4) {
        const int head = sub;
        const int row = myrow0 + r;
        const int base = (head == 0) ? 0 : (30 + 15 * (head - 1));
        float l[5];
#pragma unroll
        for (int k = 0; k < 5; ++k) l[k] = ps[r * 80 + base + k];
        const float mx = fmaxf(fmaxf(fmaxf(l[0], l[1]), fmaxf(l[2], l[3])), l[4]);
        float e[5]; float ssum = 0.0f;
#pragma unroll
        for (int k = 0; k < 5; ++k) { e[k] = expf(l[k] - mx); ssum += e[k]; }
        // inline gumbel draws
        const uint32_t g0 = keysL[t * 16 + head * 4 + 0], g1 = keysL[t * 16 + head * 4 + 1];
        int idx = 0; float best = -1e30f;
#pragma unroll
        for (int k = 0; k < 5; ++k) {
          float u = u01f(pbits(g0, g1, (uint32_t)(row * 5 + k)));
          u = fmaxf(TINYF, u * (1.0f - TINYF) + TINYF);
          const float v = l[k] - logf(-logf(u));
          if (v > best) { best = v; idx = k; }
        }
        const uint32_t n0 = keysL[t * 16 + head * 4 + 2], n1 = keysL[t * 16 + head * 4 + 3];
        if (head == 0) {
          const size_t ob = ((size_t)row * TT + t) * 30;
          float mu_lo[5], s_lo[5], mu_la[5], s_la[5], rho[5];
#pragma unroll
          for (int k = 0; k < 5; ++k) {
            mu_lo[k] = ps[r * 80 + 5 + k];
            s_lo[k] = expf(ps[r * 80 + 10 + k]);
            mu_la[k] = ps[r * 80 + 15 + k];
            s_la[k] = expf(ps[r * 80 + 20 + k]);
            rho[k] = tanhf(ps[r * 80 + 25 + k]);
          }
#pragma unroll
          for (int k = 0; k < 5; ++k) {
            out[ob + k] = e[k] / ssum;
            out[ob + 5 + k] = mu_lo[k];
            out[ob + 10 + k] = s_lo[k];
            out[ob + 15 + k] = mu_la[k];
            out[ob + 20 + k] = s_la[k];
            out[ob + 25 + k] = rho[k];
          }
          float uz0 = u01f(pbits(n0, n1, (uint32_t)(row * 2))) * 2.0f - LO_N;
          float uz1 = u01f(pbits(n0, n1, (uint32_t)(row * 2 + 1))) * 2.0f - LO_N;
          uz0 = fmaxf(-LO_N, uz0); uz1 = fmaxf(-LO_N, uz1);
          const float z0 = 1.41421356f * erfinv_f(uz0);
          const float z1 = 1.41421356f * erfinv_f(uz1);
          const float xlo = pick5a(mu_lo, idx) + pick5a(s_lo, idx) * z0;
          const float rr_ = pick5a(rho, idx);
          const float xla = pick5a(mu_la, idx) +
                            pick5a(s_la, idx) * (rr_ * z0 + sqrtf(1.0f - rr_ * rr_) * z1);
          conds[r * 8 + 0] = xlo;
          conds[r * 8 + 1] = xla;
        } else {
          const size_t ob = (size_t)BN * TT * 30 + (size_t)(head - 1) * BN * TT * 15 +
                            ((size_t)row * TT + t) * 15;
          float mu[5], sg[5];
#pragma unroll
          for (int k = 0; k < 5; ++k) {
            mu[k] = ps[r * 80 + base + 5 + k];
            sg[k] = expf(ps[r * 80 + base + 10 + k]);
          }
#pragma unroll
          for (int k = 0; k < 5; ++k) {
            out[ob + k] = e[k] / ssum;
            out[ob + 5 + k] = mu[k];
            out[ob + 10 + k] = sg[k];
          }
          float uz = u01f(pbits(n0, n1, (uint32_t)row)) * 2.0f - LO_N;
          uz = fmaxf(-LO_N, uz);
          const float zz = 1.41421356f * erfinv_f(uz);
          conds[r * 8 + 1 + head] = pick5a(mu, idx) + pick5a(sg, idx) * zz;
        }
      }
    }
    __syncthreads();
  }
}

extern "C" void kernel_launch(void* const* d_in, const int* in_sizes, int n_in,
                              void* d_out, int out_size, void* d_ws, size_t ws_size,
                              hipStream_t stream) {
  const float* conditions = (const float*)d_in[0];
  const float* state_h = (const float*)d_in[1];
  const float* state_c = (const float*)d_in[2];
  // d_in[3] = steps_n (=20, compile-time TT)
  const float* We1 = (const float*)d_in[4];
  const float* be1 = (const float*)d_in[5];
  const float* We2 = (const float*)d_in[6];
  const float* be2 = (const float*)d_in[7];
  const float* Wk  = (const float*)d_in[8];
  const float* Wr  = (const float*)d_in[9];
  const float* bl  = (const float*)d_in[10];
  const float* Wm  = (const float*)d_in[11];
  const float* bm  = (const float*)d_in[12];
  const float* Wy  = (const float*)d_in[13];
  const float* by  = (const float*)d_in[14];
  const float* Wf  = (const float*)d_in[15];
  const float* bf  = (const float*)d_in[16];
  const float* Wfa = (const float*)d_in[17];
  const float* bfa = (const float*)d_in[18];
  float* ws = (float*)d_ws;   // needs WS_END*4 ~= 6.5 MB
  float* out = (float*)d_out;

  prep1<<<dim3(83), dim3(256), 0, stream>>>(Wk, Wm, bm, Wy, by, Wf, bf, Wfa, bfa, ws);

  void* kargs[] = {
    (void*)&conditions, (void*)&state_h, (void*)&state_c,
    (void*)&We1, (void*)&be1, (void*)&We2, (void*)&be2,
    (void*)&Wk, (void*)&Wr, (void*)&bl, (void*)&ws, (void*)&out
  };
  hipLaunchCooperativeKernel((void*)decode_main, dim3(256), dim3(512), kargs, 0, stream);
}

// Round 5
// 403.909 us; speedup vs baseline: 79.8199x; 76.8302x over previous
//
#include <hip/hip_runtime.h>
#include <stdint.h>

// Problem constants
#define BN 4096
#define TT 20
#define HH 256
#define EE 128
#define KK 5
#define NCOND 5

// ws layout (float indices)
#define WS_KEYS 0                       // 320 u32: per step, 4 heads x (k1.x,k1.y,k2.x,k2.y)
#define WS_TSC  512                     // 20*1024 cumulative ts@Wk[384:404]
#define WS_WT   20992                   // 75*256 transposed head weights [o][q]
#define WS_BIAS 40192                   // 80 concat head biases
#define WS_T1   40272                   // 5*128  We1@We2
#define WS_EB2  40912                   // 128    be1@We2 + be2
#define WS_ZC   41040                   // 1024   (be1@We2+be2)@Wk1 + bl
#define WS_M    42064                   // 5*1024 We1@We2@Wk1
#define WS_WSUM 47184                   // 256*1024  Wk[128:384] + Wr
#define WS_END  309328                  // 1.24 MB

#define TINYF 1.17549435e-38f
#define LO_N  0.99999994f               // -nextafter(-1,0)

// ---------------- Threefry-2x32 (JAX-exact) ----------------
__device__ __forceinline__ void tf2(uint32_t k0, uint32_t k1, uint32_t x0, uint32_t x1,
                                    uint32_t& o0, uint32_t& o1) {
  const uint32_t ks2 = k0 ^ k1 ^ 0x1BD11BDAu;
  x0 += k0; x1 += k1;
#define RND(r) { x0 += x1; x1 = (x1 << (r)) | (x1 >> (32 - (r))); x1 ^= x0; }
  RND(13) RND(15) RND(26) RND(6)   x0 += k1;  x1 += ks2 + 1u;
  RND(17) RND(29) RND(16) RND(24)  x0 += ks2; x1 += k0 + 2u;
  RND(13) RND(15) RND(26) RND(6)   x0 += k0;  x1 += k1 + 3u;
  RND(17) RND(29) RND(16) RND(24)  x0 += k1;  x1 += ks2 + 4u;
  RND(13) RND(15) RND(26) RND(6)   x0 += ks2; x1 += k0 + 5u;
#undef RND
  o0 = x0; o1 = x1;
}

// jax_threefry_partitionable: bits[n] = a ^ b, (a,b) = threefry2x32(key, (0, n))
__device__ __forceinline__ uint32_t pbits(uint32_t k0, uint32_t k1, uint32_t n) {
  uint32_t a, b;
  tf2(k0, k1, 0u, n, a, b);
  return a ^ b;
}

__device__ __forceinline__ float u01f(uint32_t bits) {
  return __uint_as_float((bits >> 9) | 0x3f800000u) - 1.0f;
}

// XLA ErfInv32 (Giles polynomial)
__device__ __forceinline__ float erfinv_f(float x) {
  float w = -log1pf(-x * x);
  float p;
  if (w < 5.0f) {
    w = w - 2.5f;
    p = 2.81022636e-08f;
    p = 3.43273939e-07f + p * w;
    p = -3.5233877e-06f + p * w;
    p = -4.39150654e-06f + p * w;
    p = 0.00021858087f  + p * w;
    p = -0.00125372503f + p * w;
    p = -0.00417768164f + p * w;
    p = 0.246640727f    + p * w;
    p = 1.50140941f     + p * w;
  } else {
    w = sqrtf(w) - 3.0f;
    p = -0.000200214257f;
    p = 0.000100950558f + p * w;
    p = 0.00134934322f  + p * w;
    p = -0.00367342844f + p * w;
    p = 0.00573950773f  + p * w;
    p = -0.0076224613f  + p * w;
    p = 0.00943887047f  + p * w;
    p = 1.00167406f     + p * w;
    p = 2.83297682f     + p * w;
  }
  return p * x;
}

// XLA lowers logistic as 0.5 + 0.5*tanh(0.5x)
__device__ __forceinline__ float sigf(float x) { return 0.5f + 0.5f * tanhf(0.5f * x); }

__device__ __forceinline__ float pick5a(const float* a, int idx) {
  float v = a[0];
#pragma unroll
  for (int k = 1; k < 5; ++k) v = (idx == k) ? a[k] : v;
  return v;
}

// ---------------- prep_a: keys, tsc, WT/bias, T1/eb2, WSUM ----------------
__global__ __launch_bounds__(256) void prep_a(
    const float* __restrict__ Wk, const float* __restrict__ Wr,
    const float* __restrict__ We1, const float* __restrict__ be1,
    const float* __restrict__ We2, const float* __restrict__ be2,
    const float* __restrict__ Wm, const float* __restrict__ bm,
    const float* __restrict__ Wy, const float* __restrict__ by,
    const float* __restrict__ Wf, const float* __restrict__ bf,
    const float* __restrict__ Wfa, const float* __restrict__ bfa,
    float* __restrict__ ws) {
  const int bid = blockIdx.x, tid = threadIdx.x;
  if (bid == 0) {
    // partitionable split chain: key_{t+1}=tf(key,(0,0)); heads l=1..4: tf(key,(0,l));
    // per head: k1=tf(kh,(0,0)), k2=tf(kh,(0,1)).
    if (tid < 4) {
      uint32_t* keys = (uint32_t*)ws;
      const int l = tid;                 // 0=km 1=ky 2=kf 3=kfa
      uint32_t kx = 0u, ky = 42u;        // jax.random.key(42)
      for (int t = 0; t < TT; ++t) {
        uint32_t hx, hy;
        tf2(kx, ky, 0u, (uint32_t)(l + 1), hx, hy);
        uint32_t k1x, k1y, k2x, k2y;
        tf2(hx, hy, 0u, 0u, k1x, k1y);
        tf2(hx, hy, 0u, 1u, k2x, k2y);
        keys[t * 16 + l * 4 + 0] = k1x;
        keys[t * 16 + l * 4 + 1] = k1y;
        keys[t * 16 + l * 4 + 2] = k2x;
        keys[t * 16 + l * 4 + 3] = k2y;
        uint32_t nx, ny;
        tf2(kx, ky, 0u, 0u, nx, ny);
        kx = nx; ky = ny;
      }
    }
  } else if (bid <= 4) {
    const int col = (bid - 1) * 256 + tid;
    float s = 0.0f;
    for (int p = 0; p < TT; ++p) {
      s += Wk[(size_t)(EE + HH + p) * 1024 + col];
      ws[WS_TSC + p * 1024 + col] = s;
    }
  } else if (bid <= 80) {
    const int idx = (bid - 5) * 256 + tid;    // 76 blocks cover 19456 = 19200 + 75 + pad
    if (idx < 75 * 256) {
      const int o = idx >> 8, q = idx & 255;
      float v;
      if (o < 30)      v = Wm[q * 30 + o];
      else if (o < 45) v = Wy[q * 15 + (o - 30)];
      else if (o < 60) v = Wf[q * 15 + (o - 45)];
      else             v = Wfa[q * 15 + (o - 60)];
      ws[WS_WT + idx] = v;
    } else if (idx < 75 * 256 + 75) {
      const int o = idx - 75 * 256;
      float v = (o < 30) ? bm[o] : (o < 45) ? by[o - 30] : (o < 60) ? bf[o - 45] : bfa[o - 60];
      ws[WS_BIAS + o] = v;
    }
  } else if (bid == 81) {
    // T1[c][q] = sum_e We1[c][e]*We2[e][q]; eb2[q] = be2[q] + sum_e be1[e]*We2[e][q]
    if (tid < EE) {
      const int q = tid;
      float t0 = 0.f, t1 = 0.f, t2 = 0.f, t3 = 0.f, t4 = 0.f;
      float eb = be2[q];
      for (int e = 0; e < EE; ++e) {
        const float w2 = We2[e * EE + q];
        t0 = fmaf(We1[0 * EE + e], w2, t0);
        t1 = fmaf(We1[1 * EE + e], w2, t1);
        t2 = fmaf(We1[2 * EE + e], w2, t2);
        t3 = fmaf(We1[3 * EE + e], w2, t3);
        t4 = fmaf(We1[4 * EE + e], w2, t4);
        eb = fmaf(be1[e], w2, eb);
      }
      ws[WS_T1 + 0 * EE + q] = t0;
      ws[WS_T1 + 1 * EE + q] = t1;
      ws[WS_T1 + 2 * EE + q] = t2;
      ws[WS_T1 + 3 * EE + q] = t3;
      ws[WS_T1 + 4 * EE + q] = t4;
      ws[WS_EB2 + q] = eb;
    }
  } else {
    // WSUM[q][col] = Wk[128+q][col] + Wr[q][col]
    const int idx = (bid - 82) * 256 + tid;
    if (idx < 256 * 1024) {
      const int q = idx >> 10, col = idx & 1023;
      ws[WS_WSUM + idx] = Wk[(size_t)(EE + q) * 1024 + col] + Wr[(size_t)q * 1024 + col];
    }
  }
}

// ---------------- prep_b: M = T1@Wk1 (5x1024), zc = eb2@Wk1 + bl ----------------
__global__ __launch_bounds__(256) void prep_b(
    const float* __restrict__ Wk, const float* __restrict__ bl,
    float* __restrict__ ws) {
  const int col = blockIdx.x * 256 + threadIdx.x;   // 0..1023
  float m0 = 0.f, m1 = 0.f, m2 = 0.f, m3 = 0.f, m4 = 0.f;
  float zacc = bl[col];
  for (int q = 0; q < EE; ++q) {
    const float wv = Wk[(size_t)q * 1024 + col];
    m0 = fmaf(ws[WS_T1 + 0 * EE + q], wv, m0);
    m1 = fmaf(ws[WS_T1 + 1 * EE + q], wv, m1);
    m2 = fmaf(ws[WS_T1 + 2 * EE + q], wv, m2);
    m3 = fmaf(ws[WS_T1 + 3 * EE + q], wv, m3);
    m4 = fmaf(ws[WS_T1 + 4 * EE + q], wv, m4);
    zacc = fmaf(ws[WS_EB2 + q], wv, zacc);
  }
  ws[WS_M + 0 * 1024 + col] = m0;
  ws[WS_M + 1 * 1024 + col] = m1;
  ws[WS_M + 2 * 1024 + col] = m2;
  ws[WS_M + 3 * 1024 + col] = m3;
  ws[WS_M + 4 * 1024 + col] = m4;
  ws[WS_ZC + col] = zacc;
}

// ---------------- main: fully block-local 20-step decode, 16 rows/block ----------------
__global__ __launch_bounds__(512, 2) void decode_main(
    const float* __restrict__ conditions, const float* __restrict__ state_h,
    const float* __restrict__ state_c, const float* __restrict__ ws,
    float* __restrict__ out) {
  __shared__ float Msh[5 * 1024];       // 20 KB
  __shared__ float WTsh[75 * 260];      // 78 KB, stride 260 for bank spread
  __shared__ float hsh[16 * HH];        // 16 KB: state_h staging -> h
  __shared__ float psh[16 * 80];        // 5 KB
  __shared__ float conds[16 * 8];
  __shared__ uint32_t keysL[TT * 16];

  const int tid = threadIdx.x;
  const int row0 = blockIdx.x * 16;
  const int u = tid & 255;
  const int rh = tid >> 8;

  // ---- prologue staging ----
  for (int i = tid; i < 5 * 1024; i += 512) Msh[i] = ws[WS_M + i];
  for (int i = tid; i < 75 * 256; i += 512) WTsh[(i >> 8) * 260 + (i & 255)] = ws[WS_WT + i];
  for (int i = tid; i < TT * 16; i += 512) keysL[i] = ((const uint32_t*)ws)[WS_KEYS + i];
  for (int i = tid; i < 16 * NCOND; i += 512) {
    const int r = i / NCOND, c = i % NCOND;
    conds[r * 8 + c] = conditions[(size_t)(row0 + r) * (TT * NCOND) + c];  // [:,0,:]
  }
  for (int i = tid; i < 16 * HH; i += 512) hsh[i] = state_h[(size_t)row0 * HH + i];
  float sc[8];
#pragma unroll
  for (int rr = 0; rr < 8; ++rr) sc[rr] = state_c[(size_t)(row0 + rh * 8 + rr) * HH + u];
  __syncthreads();

  // ---- step-invariant cz = zc + state_h @ WSUM (registers, per unit u x 8 rows) ----
  float cz0[8], cz1[8], cz2[8], cz3[8];
  {
    const float z0c = ws[WS_ZC + u],        z1c = ws[WS_ZC + 256 + u];
    const float z2c = ws[WS_ZC + 512 + u],  z3c = ws[WS_ZC + 768 + u];
#pragma unroll
    for (int rr = 0; rr < 8; ++rr) { cz0[rr] = z0c; cz1[rr] = z1c; cz2[rr] = z2c; cz3[rr] = z3c; }
    for (int q = 0; q < HH; ++q) {
      const float w0 = ws[WS_WSUM + q * 1024 + u];
      const float w1 = ws[WS_WSUM + q * 1024 + 256 + u];
      const float w2 = ws[WS_WSUM + q * 1024 + 512 + u];
      const float w3 = ws[WS_WSUM + q * 1024 + 768 + u];
#pragma unroll
      for (int rr = 0; rr < 8; ++rr) {
        const float e = hsh[(rh * 8 + rr) * HH + q];
        cz0[rr] = fmaf(e, w0, cz0[rr]);
        cz1[rr] = fmaf(e, w1, cz1[rr]);
        cz2[rr] = fmaf(e, w2, cz2[rr]);
        cz3[rr] = fmaf(e, w3, cz3[rr]);
      }
    }
  }
  __syncthreads();   // hsh (state_h) dead -> becomes h buffer

  for (int t = 0; t < TT; ++t) {
    // ---- Phase A: z = cond@M + cz + tsc[t]; gates -> h -> hsh ----
    {
      const float t0 = ws[WS_TSC + t * 1024 + u];
      const float t1 = ws[WS_TSC + t * 1024 + 256 + u];
      const float t2 = ws[WS_TSC + t * 1024 + 512 + u];
      const float t3 = ws[WS_TSC + t * 1024 + 768 + u];
      float mA[5], mB[5], mC[5], mD[5];
#pragma unroll
      for (int c = 0; c < 5; ++c) {
        mA[c] = Msh[c * 1024 + u];
        mB[c] = Msh[c * 1024 + 256 + u];
        mC[c] = Msh[c * 1024 + 512 + u];
        mD[c] = Msh[c * 1024 + 768 + u];
      }
#pragma unroll
      for (int rr = 0; rr < 8; ++rr) {
        const int row = rh * 8 + rr;
        const float c0 = conds[row * 8 + 0], c1 = conds[row * 8 + 1], c2 = conds[row * 8 + 2],
                    c3 = conds[row * 8 + 3], c4 = conds[row * 8 + 4];
        float zi = cz0[rr] + t0, zf = cz1[rr] + t1, zg = cz2[rr] + t2, zo = cz3[rr] + t3;
        zi = fmaf(c0, mA[0], zi); zi = fmaf(c1, mA[1], zi); zi = fmaf(c2, mA[2], zi);
        zi = fmaf(c3, mA[3], zi); zi = fmaf(c4, mA[4], zi);
        zf = fmaf(c0, mB[0], zf); zf = fmaf(c1, mB[1], zf); zf = fmaf(c2, mB[2], zf);
        zf = fmaf(c3, mB[3], zf); zf = fmaf(c4, mB[4], zf);
        zg = fmaf(c0, mC[0], zg); zg = fmaf(c1, mC[1], zg); zg = fmaf(c2, mC[2], zg);
        zg = fmaf(c3, mC[3], zg); zg = fmaf(c4, mC[4], zg);
        zo = fmaf(c0, mD[0], zo); zo = fmaf(c1, mD[1], zo); zo = fmaf(c2, mD[2], zo);
        zo = fmaf(c3, mD[3], zo); zo = fmaf(c4, mD[4], zo);
        const float cv = sigf(zf) * sc[rr] + sigf(zi) * tanhf(zg);
        const float hv = sigf(zo) * tanhf(cv);
        hsh[row * HH + u] = hv;
      }
    }
    __syncthreads();
    // ---- Phase B: heads ps = h @ WT^T + bias (WT from LDS) ----
    {
      const int r = tid >> 5, jg = tid & 31;
#pragma unroll
      for (int s = 0; s < 3; ++s) {
        const int o = jg + 32 * s;
        if (o < 75) {
          float acc = ws[WS_BIAS + o];
          const float* wt = &WTsh[o * 260];
          for (int q = 0; q < HH; q += 4) {
            const float4 w = *(const float4*)&wt[q];
            const float4 hv = *(const float4*)&hsh[r * HH + q];
            acc = fmaf(hv.x, w.x, acc); acc = fmaf(hv.y, w.y, acc);
            acc = fmaf(hv.z, w.z, acc); acc = fmaf(hv.w, w.w, acc);
          }
          psh[r * 80 + o] = acc;
        }
      }
    }
    __syncthreads();
    // ---- Phase C: sampling + outputs + cond update ----
    {
      const int r = tid >> 5, sub = tid & 31;
      if (sub < 4) {
        const int head = sub;
        const int row = row0 + r;
        const int base = (head == 0) ? 0 : (30 + 15 * (head - 1));
        float l[5];
#pragma unroll
        for (int k = 0; k < 5; ++k) l[k] = psh[r * 80 + base + k];
        const float mx = fmaxf(fmaxf(fmaxf(l[0], l[1]), fmaxf(l[2], l[3])), l[4]);
        float e[5]; float ssum = 0.0f;
#pragma unroll
        for (int k = 0; k < 5; ++k) { e[k] = expf(l[k] - mx); ssum += e[k]; }
        // categorical = argmax(logits + gumbel), first-max wins
        const uint32_t g0 = keysL[t * 16 + head * 4 + 0], g1 = keysL[t * 16 + head * 4 + 1];
        int idx = 0; float best = -1e30f;
#pragma unroll
        for (int k = 0; k < 5; ++k) {
          float uv = u01f(pbits(g0, g1, (uint32_t)(row * 5 + k)));
          uv = fmaxf(TINYF, uv * (1.0f - TINYF) + TINYF);
          const float v = l[k] - logf(-logf(uv));
          if (v > best) { best = v; idx = k; }
        }
        const uint32_t n0 = keysL[t * 16 + head * 4 + 2], n1 = keysL[t * 16 + head * 4 + 3];
        if (head == 0) {
          const size_t ob = ((size_t)row * TT + t) * 30;
          float mu_lo[5], s_lo[5], mu_la[5], s_la[5], rho[5];
#pragma unroll
          for (int k = 0; k < 5; ++k) {
            mu_lo[k] = psh[r * 80 + 5 + k];
            s_lo[k] = expf(psh[r * 80 + 10 + k]);
            mu_la[k] = psh[r * 80 + 15 + k];
            s_la[k] = expf(psh[r * 80 + 20 + k]);
            rho[k] = tanhf(psh[r * 80 + 25 + k]);
          }
#pragma unroll
          for (int k = 0; k < 5; ++k) {
            out[ob + k] = e[k] / ssum;
            out[ob + 5 + k] = mu_lo[k];
            out[ob + 10 + k] = s_lo[k];
            out[ob + 15 + k] = mu_la[k];
            out[ob + 20 + k] = s_la[k];
            out[ob + 25 + k] = rho[k];
          }
          float uz0 = u01f(pbits(n0, n1, (uint32_t)(row * 2))) * 2.0f - LO_N;
          float uz1 = u01f(pbits(n0, n1, (uint32_t)(row * 2 + 1))) * 2.0f - LO_N;
          uz0 = fmaxf(-LO_N, uz0); uz1 = fmaxf(-LO_N, uz1);
          const float z0 = 1.41421356f * erfinv_f(uz0);
          const float z1 = 1.41421356f * erfinv_f(uz1);
          const float xlo = pick5a(mu_lo, idx) + pick5a(s_lo, idx) * z0;
          const float rr_ = pick5a(rho, idx);
          const float xla = pick5a(mu_la, idx) +
                            pick5a(s_la, idx) * (rr_ * z0 + sqrtf(1.0f - rr_ * rr_) * z1);
          conds[r * 8 + 0] = xlo;
          conds[r * 8 + 1] = xla;
        } else {
          const size_t ob = (size_t)BN * TT * 30 + (size_t)(head - 1) * BN * TT * 15 +
                            ((size_t)row * TT + t) * 15;
          float mu[5], sg[5];
#pragma unroll
          for (int k = 0; k < 5; ++k) {
            mu[k] = psh[r * 80 + base + 5 + k];
            sg[k] = expf(psh[r * 80 + base + 10 + k]);
          }
#pragma unroll
          for (int k = 0; k < 5; ++k) {
            out[ob + k] = e[k] / ssum;
            out[ob + 5 + k] = mu[k];
            out[ob + 10 + k] = sg[k];
          }
          float uz = u01f(pbits(n0, n1, (uint32_t)row)) * 2.0f - LO_N;
          uz = fmaxf(-LO_N, uz);
          const float zz = 1.41421356f * erfinv_f(uz);
          conds[r * 8 + 1 + head] = pick5a(mu, idx) + pick5a(sg, idx) * zz;
        }
      }
    }
    __syncthreads();
  }
}

extern "C" void kernel_launch(void* const* d_in, const int* in_sizes, int n_in,
                              void* d_out, int out_size, void* d_ws, size_t ws_size,
                              hipStream_t stream) {
  const float* conditions = (const float*)d_in[0];
  const float* state_h = (const float*)d_in[1];
  const float* state_c = (const float*)d_in[2];
  // d_in[3] = steps_n (=20, compile-time TT)
  const float* We1 = (const float*)d_in[4];
  const float* be1 = (const float*)d_in[5];
  const float* We2 = (const float*)d_in[6];
  const float* be2 = (const float*)d_in[7];
  const float* Wk  = (const float*)d_in[8];
  const float* Wr  = (const float*)d_in[9];
  const float* bl  = (const float*)d_in[10];
  const float* Wm  = (const float*)d_in[11];
  const float* bm  = (const float*)d_in[12];
  const float* Wy  = (const float*)d_in[13];
  const float* by  = (const float*)d_in[14];
  const float* Wf  = (const float*)d_in[15];
  const float* bf  = (const float*)d_in[16];
  const float* Wfa = (const float*)d_in[17];
  const float* bfa = (const float*)d_in[18];
  float* ws = (float*)d_ws;   // needs WS_END*4 ~= 1.24 MB
  float* out = (float*)d_out;

  prep_a<<<dim3(82 + 1024), dim3(256), 0, stream>>>(
      Wk, Wr, We1, be1, We2, be2, Wm, bm, Wy, by, Wf, bf, Wfa, bfa, ws);
  prep_b<<<dim3(4), dim3(256), 0, stream>>>(Wk, bl, ws);
  decode_main<<<dim3(BN / 16), dim3(512), 0, stream>>>(
      conditions, state_h, state_c, ws, out);
}